// Round 1
// baseline (996.379 us; speedup 1.0000x reference)
//
#include <hip/hip_runtime.h>
#include <math.h>

#define Bdim 64
#define Ndim 512
#define Ddim 16
#define Kdim 16
#define Edim 128
#define LN_EPS 1e-5f

// one block = 128 threads (2 waves) per (b, n) query point.
// thread e in [0,128) owns output feature e.

__device__ __forceinline__ float gelu_exact(float v) {
    return 0.5f * v * (1.0f + erff(v * 0.7071067811865476f));
}

// LayerNorm (over E=128) + exact GELU.
// On entry: acc[k] holds the raw linear output for row k, feature tid.
// On exit: acc[k] holds gelu(ln(...)) and s_h[k][tid] has the same value.
__device__ __forceinline__ void ln_gelu_store(
    float acc[Kdim],
    const float* __restrict__ g, const float* __restrict__ be,
    float (*s_h)[Edim], float (*s_stats)[2], int tid)
{
    __syncthreads();               // previous readers of s_h are done
    #pragma unroll
    for (int k = 0; k < Kdim; ++k) s_h[k][tid] = acc[k];
    __syncthreads();
    {
        const int k = tid >> 3, sub = tid & 7;   // 8 threads per row k
        float s = 0.f, s2 = 0.f;
        #pragma unroll
        for (int j = 0; j < 16; ++j) {
            float v = s_h[k][sub * 16 + j];
            s += v;
            s2 = fmaf(v, v, s2);
        }
        #pragma unroll
        for (int off = 1; off < 8; off <<= 1) {
            s  += __shfl_xor(s,  off, 64);
            s2 += __shfl_xor(s2, off, 64);
        }
        if (sub == 0) {
            float m   = s  * (1.0f / (float)Edim);
            float var = s2 * (1.0f / (float)Edim) - m * m;
            s_stats[k][0] = m;
            s_stats[k][1] = rsqrtf(var + LN_EPS);
        }
    }
    __syncthreads();
    const float gg = g[tid], bb = be[tid];
    #pragma unroll
    for (int k = 0; k < Kdim; ++k) {
        float m = s_stats[k][0], r = s_stats[k][1];
        float v = fmaf((acc[k] - m) * r, gg, bb);
        v = gelu_exact(v);
        acc[k] = v;
        s_h[k][tid] = v;
    }
    __syncthreads();
}

__global__ __launch_bounds__(128) void edgeconv_kernel(
    const float* __restrict__ x,
    const float* __restrict__ W1, const float* __restrict__ b1,
    const float* __restrict__ g1, const float* __restrict__ be1,
    const float* __restrict__ W2, const float* __restrict__ b2,
    const float* __restrict__ g2, const float* __restrict__ be2,
    const float* __restrict__ W3, const float* __restrict__ b3,
    const float* __restrict__ g3, const float* __restrict__ be3,
    float* __restrict__ out)
{
    const int n   = blockIdx.x;
    const int b   = blockIdx.y;
    const int tid = threadIdx.x;

    __shared__ __align__(16) float s_xy[Ndim * 2];          // 4 KB
    __shared__ unsigned s_idx[Kdim];
    __shared__ __align__(16) float s_feats[Kdim][2 * Ddim]; // 2 KB
    __shared__ __align__(16) float s_h[Kdim][Edim];         // 8 KB
    __shared__ float s_stats[Kdim][2];

    const float* __restrict__ xb = x + (size_t)b * Ndim * Ddim;

    // ---- stage the 2-D coordinates (dims 8,9) into LDS ----
    for (int i = tid; i < Ndim; i += 128) {
        s_xy[2 * i]     = xb[i * Ddim + 8];
        s_xy[2 * i + 1] = xb[i * Ddim + 9];
    }
    __syncthreads();

    // ---- KNN: wave 0 only. Exact fp32 mul/mul/add (no FMA contraction)
    //      so the ordering bit-matches the reference; ties by lower index
    //      via packed (d2_bits << 32) | j u64 min.
    if (tid < 64) {
        const float qx = s_xy[2 * n], qy = s_xy[2 * n + 1];
        unsigned long long key[8];
        #pragma unroll
        for (int c = 0; c < 8; ++c) {
            int j = c * 64 + tid;
            float dx = __fsub_rn(qx, s_xy[2 * j]);
            float dy = __fsub_rn(qy, s_xy[2 * j + 1]);
            float d2 = __fadd_rn(__fmul_rn(dx, dx), __fmul_rn(dy, dy));
            key[c] = ((unsigned long long)__float_as_uint(d2) << 32) | (unsigned)j;
        }
        for (int sel = 0; sel < Kdim; ++sel) {
            unsigned long long m = key[0];
            #pragma unroll
            for (int c = 1; c < 8; ++c) m = (key[c] < m) ? key[c] : m;
            #pragma unroll
            for (int off = 32; off > 0; off >>= 1) {
                unsigned long long o = __shfl_xor(m, off, 64);
                m = (o < m) ? o : m;
            }
            unsigned widx = (unsigned)m;   // uniform across the wave
            if (tid == 0) s_idx[sel] = widx;
            if ((widx & 63u) == (unsigned)tid) key[widx >> 6] = ~0ull; // owner clears
        }
    }
    __syncthreads();

    // ---- build edge features: [central(16) | neighbor-central(16)] ----
    for (int t = tid; t < Kdim * 2 * Ddim; t += 128) {
        int k = t >> 5, c = t & 31;
        float v;
        if (c < Ddim) v = xb[n * Ddim + c];
        else          v = xb[s_idx[k] * Ddim + (c - Ddim)] - xb[n * Ddim + (c - Ddim)];
        s_feats[k][c] = v;
    }
    __syncthreads();

    const int e = tid;
    float acc[Kdim];

    // ---- Layer 1: feats(16x32) @ W1(32x128) + b1 ----
    {
        const float bias = b1[e];
        #pragma unroll
        for (int k = 0; k < Kdim; ++k) acc[k] = bias;
        #pragma unroll 4
        for (int c = 0; c < 2 * Ddim; ++c) {
            float w = W1[c * Edim + e];
            #pragma unroll
            for (int k = 0; k < Kdim; ++k)
                acc[k] = fmaf(s_feats[k][c], w, acc[k]);
        }
    }
    ln_gelu_store(acc, g1, be1, s_h, s_stats, tid);

    // ---- Layer 2: h(16x128) @ W2(128x128) + b2 ----
    {
        const float bias = b2[e];
        float a2[Kdim];
        #pragma unroll
        for (int k = 0; k < Kdim; ++k) a2[k] = bias;
        for (int c0 = 0; c0 < Edim; c0 += 4) {
            float w0 = W2[(c0 + 0) * Edim + e];
            float w1 = W2[(c0 + 1) * Edim + e];
            float w2 = W2[(c0 + 2) * Edim + e];
            float w3 = W2[(c0 + 3) * Edim + e];
            #pragma unroll
            for (int k = 0; k < Kdim; ++k) {
                float4 h4 = *reinterpret_cast<const float4*>(&s_h[k][c0]);
                a2[k] = fmaf(h4.x, w0, fmaf(h4.y, w1, fmaf(h4.z, w2, fmaf(h4.w, w3, a2[k]))));
            }
        }
        #pragma unroll
        for (int k = 0; k < Kdim; ++k) acc[k] = a2[k];
    }
    ln_gelu_store(acc, g2, be2, s_h, s_stats, tid);

    // ---- Layer 3: h(16x128) @ W3(128x128) + b3 ----
    {
        const float bias = b3[e];
        float a3[Kdim];
        #pragma unroll
        for (int k = 0; k < Kdim; ++k) a3[k] = bias;
        for (int c0 = 0; c0 < Edim; c0 += 4) {
            float w0 = W3[(c0 + 0) * Edim + e];
            float w1 = W3[(c0 + 1) * Edim + e];
            float w2 = W3[(c0 + 2) * Edim + e];
            float w3 = W3[(c0 + 3) * Edim + e];
            #pragma unroll
            for (int k = 0; k < Kdim; ++k) {
                float4 h4 = *reinterpret_cast<const float4*>(&s_h[k][c0]);
                a3[k] = fmaf(h4.x, w0, fmaf(h4.y, w1, fmaf(h4.z, w2, fmaf(h4.w, w3, a3[k]))));
            }
        }
        #pragma unroll
        for (int k = 0; k < Kdim; ++k) acc[k] = a3[k];
    }
    ln_gelu_store(acc, g3, be3, s_h, s_stats, tid);

    // ---- mean over K, write output ----
    float s = 0.f;
    #pragma unroll
    for (int k = 0; k < Kdim; ++k) s += acc[k];
    out[((size_t)b * Ndim + n) * Edim + e] = s * (1.0f / (float)Kdim);
}

extern "C" void kernel_launch(void* const* d_in, const int* in_sizes, int n_in,
                              void* d_out, int out_size, void* d_ws, size_t ws_size,
                              hipStream_t stream)
{
    const float* x   = (const float*)d_in[0];
    const float* W1  = (const float*)d_in[1];
    const float* b1  = (const float*)d_in[2];
    const float* g1  = (const float*)d_in[3];
    const float* be1 = (const float*)d_in[4];
    const float* W2  = (const float*)d_in[5];
    const float* b2  = (const float*)d_in[6];
    const float* g2  = (const float*)d_in[7];
    const float* be2 = (const float*)d_in[8];
    const float* W3  = (const float*)d_in[9];
    const float* b3  = (const float*)d_in[10];
    const float* g3  = (const float*)d_in[11];
    const float* be3 = (const float*)d_in[12];
    float* out = (float*)d_out;

    dim3 grid(Ndim, Bdim);
    dim3 block(128);
    hipLaunchKernelGGL(edgeconv_kernel, grid, block, 0, stream,
                       x, W1, b1, g1, be1, W2, b2, g2, be2, W3, b3, g3, be3, out);
}

// Round 2
// 772.536 us; speedup vs baseline: 1.2898x; 1.2898x over previous
//
#include <hip/hip_runtime.h>
#include <math.h>

#define Bdim 64
#define Ndim 512
#define Ddim 16
#define Kdim 16
#define Edim 128
#define LN_EPS 1e-5f

#define PTS   8     // points per block
#define NT    8     // 16-wide N tiles over E=128
#define KS2   4     // 32-deep K steps over E=128

typedef __attribute__((ext_vector_type(8))) short bf16x8;
typedef __attribute__((ext_vector_type(4))) float f32x4;

// RNE float -> bf16 bits
__device__ __forceinline__ unsigned short f2bf(float f) {
    unsigned u = __float_as_uint(f);
    unsigned r = (u + 0x7FFFu + ((u >> 16) & 1u)) >> 16;
    return (unsigned short)r;
}

__device__ __forceinline__ float gelu_exact(float v) {
    return 0.5f * v * (1.0f + erff(v * 0.7071067811865476f));
}

// ---------------- weight pre-pack: fp32 row-major [K][128] -> bf16 B-fragments
// layout: [nt][ks][lane][j], fragment elem j of lane l = W[ks*32 + 8*(l>>4)+j][nt*16 + (l&15)]
// Wp1: 8*1*64*8 = 4096 at offset 0; Wp2: 8*4*64*8 = 16384 at 4096; Wp3 at 20480.
__global__ __launch_bounds__(256) void pack_w_kernel(
    const float* __restrict__ W1, const float* __restrict__ W2,
    const float* __restrict__ W3, unsigned short* __restrict__ wp)
{
    int idx = blockIdx.x * 256 + threadIdx.x;
    if (idx >= 36864) return;
    if (idx < 4096) {
        int t = idx;
        int nt = t >> 9, l = (t >> 3) & 63, j = t & 7;
        int k = 8 * (l >> 4) + j, n = nt * 16 + (l & 15);
        wp[idx] = f2bf(W1[k * Edim + n]);
    } else if (idx < 20480) {
        int t = idx - 4096;
        int nt = t >> 11, ks = (t >> 9) & 3, l = (t >> 3) & 63, j = t & 7;
        int k = ks * 32 + 8 * (l >> 4) + j, n = nt * 16 + (l & 15);
        wp[idx] = f2bf(W2[k * Edim + n]);
    } else {
        int t = idx - 20480;
        int nt = t >> 11, ks = (t >> 9) & 3, l = (t >> 3) & 63, j = t & 7;
        int k = ks * 32 + 8 * (l >> 4) + j, n = nt * 16 + (l & 15);
        wp[idx] = f2bf(W3[k * Edim + n]);
    }
}

// LayerNorm + exact GELU on the wave-private accumulator.
// D layout per 16x16 tile: value j of lane l is H[row = rbase + 4*(l>>4) + j][col = nt*16 + (l&15)]
__device__ __forceinline__ void ln_gelu_acc(
    f32x4 acc[2][NT], const float* __restrict__ g, const float* __restrict__ be, int lane)
{
    const int cl = lane & 15;
    float gv[NT], bev[NT];
    #pragma unroll
    for (int nt = 0; nt < NT; ++nt) { gv[nt] = g[nt*16 + cl]; bev[nt] = be[nt*16 + cl]; }

    #pragma unroll
    for (int mt = 0; mt < 2; ++mt) {
        float s[4] = {0.f,0.f,0.f,0.f}, s2[4] = {0.f,0.f,0.f,0.f};
        #pragma unroll
        for (int nt = 0; nt < NT; ++nt)
            #pragma unroll
            for (int j = 0; j < 4; ++j) {
                float v = acc[mt][nt][j];
                s[j] += v;
                s2[j] = fmaf(v, v, s2[j]);
            }
        #pragma unroll
        for (int off = 1; off < 16; off <<= 1)
            #pragma unroll
            for (int j = 0; j < 4; ++j) {
                s[j]  += __shfl_xor(s[j],  off, 64);
                s2[j] += __shfl_xor(s2[j], off, 64);
            }
        float mj[4], rj[4];
        #pragma unroll
        for (int j = 0; j < 4; ++j) {
            float m   = s[j]  * (1.0f/128.0f);
            float var = s2[j] * (1.0f/128.0f) - m * m;
            mj[j] = m;
            rj[j] = rsqrtf(var + LN_EPS);
        }
        #pragma unroll
        for (int nt = 0; nt < NT; ++nt)
            #pragma unroll
            for (int j = 0; j < 4; ++j) {
                float v = (acc[mt][nt][j] - mj[j]) * rj[j];
                v = fmaf(v, gv[nt], bev[nt]);
                acc[mt][nt][j] = gelu_exact(v);
            }
    }
}

// store acc (bf16) to swizzled H: elem col c of row r lives at r*128 + ((c>>3 ^ (r&7))<<3) + (c&7)
__device__ __forceinline__ void store_h(
    const f32x4 acc[2][NT], unsigned short* __restrict__ s_h, int wave, int lane)
{
    const int cl = lane & 15, gq = lane >> 4;
    #pragma unroll
    for (int mt = 0; mt < 2; ++mt) {
        const int rbase = 32*wave + 16*mt + 4*gq;
        #pragma unroll
        for (int nt = 0; nt < NT; ++nt) {
            const int col = nt*16 + cl;
            const int cb  = col >> 3;
            #pragma unroll
            for (int j = 0; j < 4; ++j) {
                const int row = rbase + j;
                s_h[row*128 + ((cb ^ (row & 7)) << 3) + (col & 7)] = f2bf(acc[mt][nt][j]);
            }
        }
    }
}

__global__ __launch_bounds__(256) void edgeconv_mfma(
    const float* __restrict__ x,
    const unsigned short* __restrict__ wp,
    const float* __restrict__ b1, const float* __restrict__ g1, const float* __restrict__ be1,
    const float* __restrict__ b2, const float* __restrict__ g2, const float* __restrict__ be2,
    const float* __restrict__ b3, const float* __restrict__ g3, const float* __restrict__ be3,
    float* __restrict__ out)
{
    const int tid  = threadIdx.x;
    const int wave = tid >> 6, lane = tid & 63;
    const int bp = blockIdx.x;
    const int b  = bp >> 6;              // 64 blocks per batch element
    const int n0 = (bp & 63) * PTS;

    __shared__ __align__(16) float s_xy[Ndim * 2];                 // 4 KB
    __shared__ unsigned s_idx[PTS][Kdim];                          // 0.5 KB
    __shared__ __align__(16) unsigned short s_feats[PTS * 16 * 40];// 10 KB, pitch 40 bf16
    __shared__ __align__(16) unsigned short s_h[128 * 128];        // 32 KB, XOR-swizzled

    const float* __restrict__ xb = x + (size_t)b * (Ndim * Ddim);

    // ---- stage 2-D coords ----
    for (int i = tid; i < Ndim; i += 256) {
        s_xy[2*i]   = xb[i * Ddim + 8];
        s_xy[2*i+1] = xb[i * Ddim + 9];
    }
    __syncthreads();

    // ---- KNN (wave w handles its 2 points). Exact fp32 mul/mul/add; ties by lower idx. ----
    #pragma unroll
    for (int pp = 0; pp < 2; ++pp) {
        const int p = 2*wave + pp;
        const int n = n0 + p;
        const float qx = s_xy[2*n], qy = s_xy[2*n+1];
        unsigned long long key[8];
        #pragma unroll
        for (int c = 0; c < 8; ++c) {
            int j = c * 64 + lane;
            float dx = __fsub_rn(qx, s_xy[2*j]);
            float dy = __fsub_rn(qy, s_xy[2*j+1]);
            float d2 = __fadd_rn(__fmul_rn(dx,dx), __fmul_rn(dy,dy));
            key[c] = ((unsigned long long)__float_as_uint(d2) << 32) | (unsigned)j;
        }
        for (int sel = 0; sel < Kdim; ++sel) {
            unsigned long long m = key[0];
            #pragma unroll
            for (int c = 1; c < 8; ++c) m = (key[c] < m) ? key[c] : m;
            #pragma unroll
            for (int off = 32; off > 0; off >>= 1) {
                unsigned long long o = __shfl_xor(m, off, 64);
                m = (o < m) ? o : m;
            }
            unsigned widx = (unsigned)m;
            if (lane == 0) s_idx[p][sel] = widx;
            const bool owner = ((widx & 63u) == (unsigned)lane);
            const unsigned co = widx >> 6;
            #pragma unroll
            for (int c = 0; c < 8; ++c)
                if (owner && co == (unsigned)c) key[c] = ~0ull;   // static index (no scratch)
        }
    }
    __syncthreads();

    // ---- edge features -> LDS bf16, [p][neighbor k][32], pitch 40 ----
    for (int t = tid; t < PTS * 16 * 32; t += 256) {
        int p = t >> 9, r = (t >> 5) & 15, c = t & 31;
        int n = n0 + p;
        float v;
        if (c < 16) v = xb[n * Ddim + c];
        else {
            int nb = (int)s_idx[p][r];
            v = xb[nb * Ddim + (c - 16)] - xb[n * Ddim + (c - 16)];
        }
        s_feats[p * 640 + r * 40 + c] = f2bf(v);
    }
    __syncthreads();
    // After this point s_h rows are wave-private (wave w touches rows 32w..32w+31 only):
    // no further __syncthreads needed.

    const int cl = lane & 15, gq = lane >> 4;
    f32x4 acc[2][NT];

    // ================= Layer 1: feats(16x32) @ W1 =================
    {
        float bv[NT];
        #pragma unroll
        for (int nt = 0; nt < NT; ++nt) bv[nt] = b1[nt*16 + cl];
        bf16x8 a1[2];
        #pragma unroll
        for (int mt = 0; mt < 2; ++mt) {
            int p = 2*wave + mt;
            a1[mt] = *(const bf16x8*)(&s_feats[p*640 + cl*40 + (gq << 3)]);
        }
        #pragma unroll
        for (int nt = 0; nt < NT; ++nt) {
            bf16x8 bfr = *(const bf16x8*)(wp + (nt*64 + lane)*8);
            #pragma unroll
            for (int mt = 0; mt < 2; ++mt) {
                f32x4 c = {bv[nt], bv[nt], bv[nt], bv[nt]};
                acc[mt][nt] = __builtin_amdgcn_mfma_f32_16x16x32_bf16(a1[mt], bfr, c, 0, 0, 0);
            }
        }
    }
    ln_gelu_acc(acc, g1, be1, lane);
    store_h(acc, s_h, wave, lane);

    // ================= Layers 2 and 3: H(32x128) @ W(128x128) =================
    #pragma unroll 1
    for (int layer = 0; layer < 2; ++layer) {
        const unsigned short* wpL = wp + (layer == 0 ? 4096 : 20480);
        const float* bL  = (layer == 0) ? b2  : b3;
        const float* gL  = (layer == 0) ? g2  : g3;
        const float* beL = (layer == 0) ? be2 : be3;

        float bv[NT];
        #pragma unroll
        for (int nt = 0; nt < NT; ++nt) bv[nt] = bL[nt*16 + cl];

        bf16x8 a[2][KS2];
        #pragma unroll
        for (int mt = 0; mt < 2; ++mt) {
            const int row = 32*wave + 16*mt + cl;
            #pragma unroll
            for (int ks = 0; ks < KS2; ++ks) {
                const int cb = ks*4 + gq;
                a[mt][ks] = *(const bf16x8*)(&s_h[row*128 + ((cb ^ (row & 7)) << 3)]);
            }
        }
        #pragma unroll
        for (int nt = 0; nt < NT; ++nt) {
            bf16x8 bfr[KS2];
            #pragma unroll
            for (int ks = 0; ks < KS2; ++ks)
                bfr[ks] = *(const bf16x8*)(wpL + ((nt*KS2 + ks)*64 + lane)*8);
            #pragma unroll
            for (int mt = 0; mt < 2; ++mt) {
                f32x4 c = {bv[nt], bv[nt], bv[nt], bv[nt]};
                #pragma unroll
                for (int ks = 0; ks < KS2; ++ks)
                    c = __builtin_amdgcn_mfma_f32_16x16x32_bf16(a[mt][ks], bfr[ks], c, 0, 0, 0);
                acc[mt][nt] = c;
            }
        }
        ln_gelu_acc(acc, gL, beL, lane);
        if (layer == 0) store_h(acc, s_h, wave, lane);
    }

    // ================= mean over K=16 rows, write out =================
    #pragma unroll
    for (int mt = 0; mt < 2; ++mt) {
        const int n = n0 + 2*wave + mt;
        #pragma unroll
        for (int nt = 0; nt < NT; ++nt) {
            float sv = acc[mt][nt][0] + acc[mt][nt][1] + acc[mt][nt][2] + acc[mt][nt][3];
            sv += __shfl_xor(sv, 16, 64);
            sv += __shfl_xor(sv, 32, 64);
            if (gq == (nt >> 1))    // 16 lanes of the owning quad write 64B
                out[((size_t)b * Ndim + n) * Edim + nt*16 + cl] = sv * (1.0f/16.0f);
        }
    }
}

extern "C" void kernel_launch(void* const* d_in, const int* in_sizes, int n_in,
                              void* d_out, int out_size, void* d_ws, size_t ws_size,
                              hipStream_t stream)
{
    const float* x   = (const float*)d_in[0];
    const float* W1  = (const float*)d_in[1];
    const float* b1  = (const float*)d_in[2];
    const float* g1  = (const float*)d_in[3];
    const float* be1 = (const float*)d_in[4];
    const float* W2  = (const float*)d_in[5];
    const float* b2  = (const float*)d_in[6];
    const float* g2  = (const float*)d_in[7];
    const float* be2 = (const float*)d_in[8];
    const float* W3  = (const float*)d_in[9];
    const float* b3  = (const float*)d_in[10];
    const float* g3  = (const float*)d_in[11];
    const float* be3 = (const float*)d_in[12];
    float* out = (float*)d_out;
    unsigned short* wp = (unsigned short*)d_ws;

    hipLaunchKernelGGL(pack_w_kernel, dim3(144), dim3(256), 0, stream, W1, W2, W3, wp);
    hipLaunchKernelGGL(edgeconv_mfma, dim3((Bdim * Ndim) / PTS), dim3(256), 0, stream,
                       x, wp, b1, g1, be1, b2, g2, be2, b3, g3, be3, out);
}

// Round 3
// 263.323 us; speedup vs baseline: 3.7839x; 2.9338x over previous
//
#include <hip/hip_runtime.h>
#include <math.h>

#define Bdim 64
#define Ndim 512
#define Ddim 16
#define Kdim 16
#define Edim 128
#define LN_EPS 1e-5f

#define PTS   4     // points per block (2 per wave)
#define NT    8     // 16-wide N tiles over E=128
#define KS2   4     // 32-deep K steps over E=128

typedef __attribute__((ext_vector_type(8))) short bf16x8;
typedef __attribute__((ext_vector_type(4))) float f32x4;

// RNE float -> bf16 bits
__device__ __forceinline__ unsigned short f2bf(float f) {
    unsigned u = __float_as_uint(f);
    unsigned r = (u + 0x7FFFu + ((u >> 16) & 1u)) >> 16;
    return (unsigned short)r;
}

// GELU, tanh-form via sigmoid identity: 0.5x(1+tanh(g)) = x*sigmoid(2g),
// 2g = x*(1.5957691 + 0.0713548*x^2).  |err vs exact| <= ~4e-4.
// ~7 VALU ops: mul, fma, mul, exp, add, rcp, mul.
__device__ __forceinline__ float gelu_fast(float x) {
    float x2 = x * x;
    float t  = fmaf(x2, -0.0713548162f, -1.5957691216f);
    float e  = __expf(x * t);                       // e^{-2g}
    return x * __builtin_amdgcn_rcpf(1.0f + e);
}

// ---------------- weight pre-pack: fp32 row-major [K][128] -> bf16 B-fragments
// layout: [nt][ks][lane][j], fragment elem j of lane l = W[ks*32 + 8*(l>>4)+j][nt*16 + (l&15)]
__global__ __launch_bounds__(256) void pack_w_kernel(
    const float* __restrict__ W1, const float* __restrict__ W2,
    const float* __restrict__ W3, unsigned short* __restrict__ wp)
{
    int idx = blockIdx.x * 256 + threadIdx.x;
    if (idx >= 36864) return;
    if (idx < 4096) {
        int t = idx;
        int nt = t >> 9, l = (t >> 3) & 63, j = t & 7;
        int k = 8 * (l >> 4) + j, n = nt * 16 + (l & 15);
        wp[idx] = f2bf(W1[k * Edim + n]);
    } else if (idx < 20480) {
        int t = idx - 4096;
        int nt = t >> 11, ks = (t >> 9) & 3, l = (t >> 3) & 63, j = t & 7;
        int k = ks * 32 + 8 * (l >> 4) + j, n = nt * 16 + (l & 15);
        wp[idx] = f2bf(W2[k * Edim + n]);
    } else {
        int t = idx - 20480;
        int nt = t >> 11, ks = (t >> 9) & 3, l = (t >> 3) & 63, j = t & 7;
        int k = ks * 32 + 8 * (l >> 4) + j, n = nt * 16 + (l & 15);
        wp[idx] = f2bf(W3[k * Edim + n]);
    }
}

// LayerNorm + GELU on the wave-private accumulator.
// D layout per 16x16 tile: value j of lane l is H[row = rbase + 4*(l>>4) + j][col = nt*16 + (l&15)]
__device__ __forceinline__ void ln_gelu_acc(
    f32x4 acc[2][NT], const float* __restrict__ g, const float* __restrict__ be, int lane)
{
    const int cl = lane & 15;
    float gv[NT], bev[NT];
    #pragma unroll
    for (int nt = 0; nt < NT; ++nt) { gv[nt] = g[nt*16 + cl]; bev[nt] = be[nt*16 + cl]; }

    #pragma unroll
    for (int mt = 0; mt < 2; ++mt) {
        float s[4] = {0.f,0.f,0.f,0.f}, s2[4] = {0.f,0.f,0.f,0.f};
        #pragma unroll
        for (int nt = 0; nt < NT; ++nt)
            #pragma unroll
            for (int j = 0; j < 4; ++j) {
                float v = acc[mt][nt][j];
                s[j] += v;
                s2[j] = fmaf(v, v, s2[j]);
            }
        #pragma unroll
        for (int off = 1; off < 16; off <<= 1)
            #pragma unroll
            for (int j = 0; j < 4; ++j) {
                s[j]  += __shfl_xor(s[j],  off, 64);
                s2[j] += __shfl_xor(s2[j], off, 64);
            }
        float mj[4], rj[4];
        #pragma unroll
        for (int j = 0; j < 4; ++j) {
            float m   = s[j]  * (1.0f/128.0f);
            float var = s2[j] * (1.0f/128.0f) - m * m;
            mj[j] = m;
            rj[j] = __builtin_amdgcn_rsqf(var + LN_EPS);
        }
        #pragma unroll
        for (int nt = 0; nt < NT; ++nt)
            #pragma unroll
            for (int j = 0; j < 4; ++j) {
                float v = (acc[mt][nt][j] - mj[j]) * rj[j];
                v = fmaf(v, gv[nt], bev[nt]);
                acc[mt][nt][j] = gelu_fast(v);
            }
    }
}

// store acc (bf16) to swizzled H: elem col c of row r lives at r*128 + ((c>>3 ^ (r&7))<<3) + (c&7)
__device__ __forceinline__ void store_h(
    const f32x4 acc[2][NT], unsigned short* __restrict__ s_h, int wave, int lane)
{
    const int cl = lane & 15, gq = lane >> 4;
    #pragma unroll
    for (int mt = 0; mt < 2; ++mt) {
        const int rbase = 32*wave + 16*mt + 4*gq;
        #pragma unroll
        for (int nt = 0; nt < NT; ++nt) {
            const int col = nt*16 + cl;
            const int cb  = col >> 3;
            #pragma unroll
            for (int j = 0; j < 4; ++j) {
                const int row = rbase + j;
                s_h[row*128 + ((cb ^ (row & 7)) << 3) + (col & 7)] = f2bf(acc[mt][nt][j]);
            }
        }
    }
}

__global__ __launch_bounds__(128, 3) void edgeconv_mfma(
    const float* __restrict__ x,
    const unsigned short* __restrict__ wp,
    const float* __restrict__ b1, const float* __restrict__ g1, const float* __restrict__ be1,
    const float* __restrict__ b2, const float* __restrict__ g2, const float* __restrict__ be2,
    const float* __restrict__ b3, const float* __restrict__ g3, const float* __restrict__ be3,
    float* __restrict__ out)
{
    const int tid  = threadIdx.x;
    const int wave = tid >> 6, lane = tid & 63;
    const int bp = blockIdx.x;
    const int b  = bp >> 7;              // 128 blocks per batch element
    const int n0 = (bp & 127) * PTS;

    __shared__ __align__(16) float s_xy[Ndim * 2];                 // 4 KB
    __shared__ unsigned s_idx[PTS][Kdim];                          // 256 B
    __shared__ __align__(16) unsigned short s_feats[PTS * 16 * 40];// 5 KB, pitch 40 bf16
    __shared__ __align__(16) unsigned short s_h[64 * 128];         // 16 KB, XOR-swizzled

    const float* __restrict__ xb = x + (size_t)b * (Ndim * Ddim);

    // ---- stage 2-D coords ----
    for (int i = tid; i < Ndim; i += 128) {
        s_xy[2*i]   = xb[i * Ddim + 8];
        s_xy[2*i+1] = xb[i * Ddim + 9];
    }
    __syncthreads();

    // ---- KNN (wave w handles its 2 points). Exact fp32 mul/mul/add; ties by lower idx. ----
    #pragma unroll
    for (int pp = 0; pp < 2; ++pp) {
        const int p = 2*wave + pp;
        const int n = n0 + p;
        const float qx = s_xy[2*n], qy = s_xy[2*n+1];
        unsigned long long key[8];
        #pragma unroll
        for (int c = 0; c < 8; ++c) {
            int j = c * 64 + lane;
            float dx = __fsub_rn(qx, s_xy[2*j]);
            float dy = __fsub_rn(qy, s_xy[2*j+1]);
            float d2 = __fadd_rn(__fmul_rn(dx,dx), __fmul_rn(dy,dy));
            key[c] = ((unsigned long long)__float_as_uint(d2) << 32) | (unsigned)j;
        }
        for (int sel = 0; sel < Kdim; ++sel) {
            unsigned long long m = key[0];
            #pragma unroll
            for (int c = 1; c < 8; ++c) m = (key[c] < m) ? key[c] : m;
            #pragma unroll
            for (int off = 32; off > 0; off >>= 1) {
                unsigned long long o = __shfl_xor(m, off, 64);
                m = (o < m) ? o : m;
            }
            unsigned widx = (unsigned)m;
            if (lane == 0) s_idx[p][sel] = widx;
            const bool owner = ((widx & 63u) == (unsigned)lane);
            const unsigned co = widx >> 6;
            #pragma unroll
            for (int c = 0; c < 8; ++c)
                if (owner && co == (unsigned)c) key[c] = ~0ull;   // static index (no scratch)
        }
    }
    __syncthreads();

    // ---- edge features -> LDS bf16, [p][neighbor k][32], pitch 40 ----
    for (int t = tid; t < PTS * 16 * 32; t += 128) {
        int p = t >> 9, r = (t >> 5) & 15, c = t & 31;
        int n = n0 + p;
        float v;
        if (c < 16) v = xb[n * Ddim + c];
        else {
            int nb = (int)s_idx[p][r];
            v = xb[nb * Ddim + (c - 16)] - xb[n * Ddim + (c - 16)];
        }
        s_feats[p * 640 + r * 40 + c] = f2bf(v);
    }
    __syncthreads();
    // After this point s_h rows are wave-private (wave w touches rows 32w..32w+31 only):
    // no further __syncthreads needed.

    const int cl = lane & 15, gq = lane >> 4;
    f32x4 acc[2][NT];

    // ================= Layer 1: feats(16x32) @ W1 =================
    {
        float bv[NT];
        #pragma unroll
        for (int nt = 0; nt < NT; ++nt) bv[nt] = b1[nt*16 + cl];
        bf16x8 a1[2];
        #pragma unroll
        for (int mt = 0; mt < 2; ++mt) {
            int p = 2*wave + mt;
            a1[mt] = *(const bf16x8*)(&s_feats[p*640 + cl*40 + (gq << 3)]);
        }
        #pragma unroll
        for (int nt = 0; nt < NT; ++nt) {
            bf16x8 bfr = *(const bf16x8*)(wp + (nt*64 + lane)*8);
            #pragma unroll
            for (int mt = 0; mt < 2; ++mt) {
                f32x4 c = {bv[nt], bv[nt], bv[nt], bv[nt]};
                acc[mt][nt] = __builtin_amdgcn_mfma_f32_16x16x32_bf16(a1[mt], bfr, c, 0, 0, 0);
            }
        }
    }
    ln_gelu_acc(acc, g1, be1, lane);
    store_h(acc, s_h, wave, lane);

    // ================= Layers 2 and 3: H(32x128) @ W(128x128) =================
    #pragma unroll 1
    for (int layer = 0; layer < 2; ++layer) {
        const unsigned short* wpL = wp + (layer == 0 ? 4096 : 20480);
        const float* bL  = (layer == 0) ? b2  : b3;
        const float* gL  = (layer == 0) ? g2  : g3;
        const float* beL = (layer == 0) ? be2 : be3;

        float bv[NT];
        #pragma unroll
        for (int nt = 0; nt < NT; ++nt) bv[nt] = bL[nt*16 + cl];

        bf16x8 a[2][KS2];
        #pragma unroll
        for (int mt = 0; mt < 2; ++mt) {
            const int row = 32*wave + 16*mt + cl;
            #pragma unroll
            for (int ks = 0; ks < KS2; ++ks) {
                const int cb = ks*4 + gq;
                a[mt][ks] = *(const bf16x8*)(&s_h[row*128 + ((cb ^ (row & 7)) << 3)]);
            }
        }
        #pragma unroll
        for (int nt = 0; nt < NT; ++nt) {
            bf16x8 bfr[KS2];
            #pragma unroll
            for (int ks = 0; ks < KS2; ++ks)
                bfr[ks] = *(const bf16x8*)(wpL + ((nt*KS2 + ks)*64 + lane)*8);
            #pragma unroll
            for (int mt = 0; mt < 2; ++mt) {
                f32x4 c = {bv[nt], bv[nt], bv[nt], bv[nt]};
                #pragma unroll
                for (int ks = 0; ks < KS2; ++ks)
                    c = __builtin_amdgcn_mfma_f32_16x16x32_bf16(a[mt][ks], bfr[ks], c, 0, 0, 0);
                acc[mt][nt] = c;
            }
        }
        ln_gelu_acc(acc, gL, beL, lane);
        if (layer == 0) store_h(acc, s_h, wave, lane);
    }

    // ================= mean over K=16 rows, write out =================
    #pragma unroll
    for (int mt = 0; mt < 2; ++mt) {
        const int n = n0 + 2*wave + mt;
        #pragma unroll
        for (int nt = 0; nt < NT; ++nt) {
            float sv = acc[mt][nt][0] + acc[mt][nt][1] + acc[mt][nt][2] + acc[mt][nt][3];
            sv += __shfl_xor(sv, 16, 64);
            sv += __shfl_xor(sv, 32, 64);
            if (gq == (nt >> 1))    // 16 lanes of the owning quad write 64B
                out[((size_t)b * Ndim + n) * Edim + nt*16 + cl] = sv * (1.0f/16.0f);
        }
    }
}

extern "C" void kernel_launch(void* const* d_in, const int* in_sizes, int n_in,
                              void* d_out, int out_size, void* d_ws, size_t ws_size,
                              hipStream_t stream)
{
    const float* x   = (const float*)d_in[0];
    const float* W1  = (const float*)d_in[1];
    const float* b1  = (const float*)d_in[2];
    const float* g1  = (const float*)d_in[3];
    const float* be1 = (const float*)d_in[4];
    const float* W2  = (const float*)d_in[5];
    const float* b2  = (const float*)d_in[6];
    const float* g2  = (const float*)d_in[7];
    const float* be2 = (const float*)d_in[8];
    const float* W3  = (const float*)d_in[9];
    const float* b3  = (const float*)d_in[10];
    const float* g3  = (const float*)d_in[11];
    const float* be3 = (const float*)d_in[12];
    float* out = (float*)d_out;
    unsigned short* wp = (unsigned short*)d_ws;

    hipLaunchKernelGGL(pack_w_kernel, dim3(144), dim3(256), 0, stream, W1, W2, W3, wp);
    hipLaunchKernelGGL(edgeconv_mfma, dim3((Bdim * Ndim) / PTS), dim3(128), 0, stream,
                       x, wp, b1, g1, be1, b2, g2, be2, b3, g3, be3, out);
}

// Round 4
// 254.422 us; speedup vs baseline: 3.9162x; 1.0350x over previous
//
#include <hip/hip_runtime.h>
#include <math.h>

#define Bdim 64
#define Ndim 512
#define Ddim 16
#define Kdim 16
#define Edim 128
#define LN_EPS 1e-5f

#define PTS   4     // points per block (2 per wave)
#define NT    8     // 16-wide N tiles over E=128
#define KS2   4     // 32-deep K steps over E=128

typedef __attribute__((ext_vector_type(8))) short bf16x8;
typedef __attribute__((ext_vector_type(4))) float f32x4;

// RNE float -> bf16 bits
__device__ __forceinline__ unsigned short f2bf(float f) {
    unsigned u = __float_as_uint(f);
    unsigned r = (u + 0x7FFFu + ((u >> 16) & 1u)) >> 16;
    return (unsigned short)r;
}

// GELU, tanh-form via sigmoid identity: |err vs exact| <= ~4e-4, ~7 VALU ops.
__device__ __forceinline__ float gelu_fast(float x) {
    float x2 = x * x;
    float t  = fmaf(x2, -0.0713548162f, -1.5957691216f);
    float e  = __expf(x * t);                       // e^{-2g}
    return x * __builtin_amdgcn_rcpf(1.0f + e);
}

// ---------------- weight pre-pack: fp32 row-major [K][128] -> bf16 B-fragments
// layout: [nt][ks][lane][j], fragment elem j of lane l = W[ks*32 + 8*(l>>4)+j][nt*16 + (l&15)]
__global__ __launch_bounds__(256) void pack_w_kernel(
    const float* __restrict__ W1, const float* __restrict__ W2,
    const float* __restrict__ W3, unsigned short* __restrict__ wp)
{
    int idx = blockIdx.x * 256 + threadIdx.x;
    if (idx >= 36864) return;
    if (idx < 4096) {
        int t = idx;
        int nt = t >> 9, l = (t >> 3) & 63, j = t & 7;
        int k = 8 * (l >> 4) + j, n = nt * 16 + (l & 15);
        wp[idx] = f2bf(W1[k * Edim + n]);
    } else if (idx < 20480) {
        int t = idx - 4096;
        int nt = t >> 11, ks = (t >> 9) & 3, l = (t >> 3) & 63, j = t & 7;
        int k = ks * 32 + 8 * (l >> 4) + j, n = nt * 16 + (l & 15);
        wp[idx] = f2bf(W2[k * Edim + n]);
    } else {
        int t = idx - 20480;
        int nt = t >> 11, ks = (t >> 9) & 3, l = (t >> 3) & 63, j = t & 7;
        int k = ks * 32 + 8 * (l >> 4) + j, n = nt * 16 + (l & 15);
        wp[idx] = f2bf(W3[k * Edim + n]);
    }
}

// LayerNorm + GELU on the wave-private accumulator.
// D layout per 16x16 tile: value j of lane l is H[row = rbase + 4*(l>>4) + j][col = nt*16 + (l&15)]
__device__ __forceinline__ void ln_gelu_acc(
    f32x4 acc[2][NT], const float* __restrict__ g, const float* __restrict__ be, int lane)
{
    const int cl = lane & 15;
    float gv[NT], bev[NT];
    #pragma unroll
    for (int nt = 0; nt < NT; ++nt) { gv[nt] = g[nt*16 + cl]; bev[nt] = be[nt*16 + cl]; }

    #pragma unroll
    for (int mt = 0; mt < 2; ++mt) {
        float s[4] = {0.f,0.f,0.f,0.f}, s2[4] = {0.f,0.f,0.f,0.f};
        #pragma unroll
        for (int nt = 0; nt < NT; ++nt)
            #pragma unroll
            for (int j = 0; j < 4; ++j) {
                float v = acc[mt][nt][j];
                s[j] += v;
                s2[j] = fmaf(v, v, s2[j]);
            }
        #pragma unroll
        for (int off = 1; off < 16; off <<= 1)
            #pragma unroll
            for (int j = 0; j < 4; ++j) {
                s[j]  += __shfl_xor(s[j],  off, 64);
                s2[j] += __shfl_xor(s2[j], off, 64);
            }
        float mj[4], rj[4];
        #pragma unroll
        for (int j = 0; j < 4; ++j) {
            float m   = s[j]  * (1.0f/128.0f);
            float var = s2[j] * (1.0f/128.0f) - m * m;
            mj[j] = m;
            rj[j] = __builtin_amdgcn_rsqf(var + LN_EPS);
        }
        #pragma unroll
        for (int nt = 0; nt < NT; ++nt)
            #pragma unroll
            for (int j = 0; j < 4; ++j) {
                float v = (acc[mt][nt][j] - mj[j]) * rj[j];
                v = fmaf(v, gv[nt], bev[nt]);
                acc[mt][nt][j] = gelu_fast(v);
            }
    }
}

// store acc (bf16) to swizzled H: elem col c of row r lives at r*128 + ((c>>3 ^ (r&7))<<3) + (c&7)
__device__ __forceinline__ void store_h(
    const f32x4 acc[2][NT], unsigned short* __restrict__ s_h, int wave, int lane)
{
    const int cl = lane & 15, gq = lane >> 4;
    #pragma unroll
    for (int mt = 0; mt < 2; ++mt) {
        const int rbase = 32*wave + 16*mt + 4*gq;
        #pragma unroll
        for (int nt = 0; nt < NT; ++nt) {
            const int col = nt*16 + cl;
            const int cb  = col >> 3;
            #pragma unroll
            for (int j = 0; j < 4; ++j) {
                const int row = rbase + j;
                s_h[row*128 + ((cb ^ (row & 7)) << 3) + (col & 7)] = f2bf(acc[mt][nt][j]);
            }
        }
    }
}

__global__ __launch_bounds__(128, 4) void edgeconv_mfma(
    const float* __restrict__ x,
    const unsigned short* __restrict__ wp,
    const float* __restrict__ b1, const float* __restrict__ g1, const float* __restrict__ be1,
    const float* __restrict__ b2, const float* __restrict__ g2, const float* __restrict__ be2,
    const float* __restrict__ b3, const float* __restrict__ g3, const float* __restrict__ be3,
    float* __restrict__ out)
{
    const int tid  = threadIdx.x;
    const int wave = tid >> 6, lane = tid & 63;
    const int bp = blockIdx.x;
    const int b  = bp >> 7;              // 128 blocks per batch element
    const int n0 = (bp & 127) * PTS;

    // only LDS: wave-private H rows (wave w owns rows 32w..32w+31). No barriers anywhere.
    __shared__ __align__(16) unsigned short s_h[64 * 128];         // 16 KB, XOR-swizzled

    const float* __restrict__ xb = x + (size_t)b * (Ndim * Ddim);
    const int cl = lane & 15, gq = lane >> 4;

    // ---- candidate xy coords into registers: lane holds points {c*64+lane} ----
    float cxr[8], cyr[8];
    #pragma unroll
    for (int c = 0; c < 8; ++c) {
        const float2 p2 = *(const float2*)(xb + (c * 64 + lane) * Ddim + 8);
        cxr[c] = p2.x; cyr[c] = p2.y;
    }

    // ---- KNN (this wave's 2 points). Exact fp32 mul/mul/add; ties by lower idx.
    //      Lane cl captures the cl-th selected neighbor index in my_nb[pp].
    unsigned my_nb[2];
    #pragma unroll
    for (int pp = 0; pp < 2; ++pp) {
        const int n = n0 + 2*wave + pp;
        const float qx = xb[n * Ddim + 8], qy = xb[n * Ddim + 9];
        unsigned long long key[8];
        #pragma unroll
        for (int c = 0; c < 8; ++c) {
            int j = c * 64 + lane;
            float dx = __fsub_rn(qx, cxr[c]);
            float dy = __fsub_rn(qy, cyr[c]);
            float d2 = __fadd_rn(__fmul_rn(dx,dx), __fmul_rn(dy,dy));
            key[c] = ((unsigned long long)__float_as_uint(d2) << 32) | (unsigned)j;
        }
        for (int sel = 0; sel < Kdim; ++sel) {
            unsigned long long m = key[0];
            #pragma unroll
            for (int c = 1; c < 8; ++c) m = (key[c] < m) ? key[c] : m;
            #pragma unroll
            for (int off = 32; off > 0; off >>= 1) {
                unsigned long long o = __shfl_xor(m, off, 64);
                m = (o < m) ? o : m;
            }
            unsigned widx = (unsigned)m;
            if ((lane & 15) == sel) my_nb[pp] = widx;   // capture for all 4 gq quads
            const bool owner = ((widx & 63u) == (unsigned)lane);
            const unsigned co = widx >> 6;
            #pragma unroll
            for (int c = 0; c < 8; ++c)
                if (owner && co == (unsigned)c) key[c] = ~0ull;   // static index (no scratch)
        }
    }

    f32x4 acc[2][NT];

    // ================= Layer 1: feats(16x32) @ W1, A-fragment built in registers =================
    {
        bf16x8 a1[2];
        const int off8 = (gq & 1) * 8;
        #pragma unroll
        for (int mt = 0; mt < 2; ++mt) {
            const int n = n0 + 2*wave + mt;
            const float* pc = xb + n * Ddim + off8;
            const float* pn = xb + (int)my_nb[mt] * Ddim + off8;
            float4 c0 = *(const float4*)(pc);
            float4 c1 = *(const float4*)(pc + 4);
            float4 v0 = *(const float4*)(pn);
            float4 v1 = *(const float4*)(pn + 4);
            const bool diff = (gq >= 2);
            float e0 = diff ? (v0.x - c0.x) : c0.x;
            float e1 = diff ? (v0.y - c0.y) : c0.y;
            float e2 = diff ? (v0.z - c0.z) : c0.z;
            float e3 = diff ? (v0.w - c0.w) : c0.w;
            float e4 = diff ? (v1.x - c1.x) : c1.x;
            float e5 = diff ? (v1.y - c1.y) : c1.y;
            float e6 = diff ? (v1.z - c1.z) : c1.z;
            float e7 = diff ? (v1.w - c1.w) : c1.w;
            bf16x8 f;
            f[0] = (short)f2bf(e0); f[1] = (short)f2bf(e1);
            f[2] = (short)f2bf(e2); f[3] = (short)f2bf(e3);
            f[4] = (short)f2bf(e4); f[5] = (short)f2bf(e5);
            f[6] = (short)f2bf(e6); f[7] = (short)f2bf(e7);
            a1[mt] = f;
        }
        float bv[NT];
        #pragma unroll
        for (int nt = 0; nt < NT; ++nt) bv[nt] = b1[nt*16 + cl];
        #pragma unroll
        for (int nt = 0; nt < NT; ++nt) {
            bf16x8 bfr = *(const bf16x8*)(wp + (nt*64 + lane)*8);
            #pragma unroll
            for (int mt = 0; mt < 2; ++mt) {
                f32x4 c = {bv[nt], bv[nt], bv[nt], bv[nt]};
                acc[mt][nt] = __builtin_amdgcn_mfma_f32_16x16x32_bf16(a1[mt], bfr, c, 0, 0, 0);
            }
        }
    }
    ln_gelu_acc(acc, g1, be1, lane);
    store_h(acc, s_h, wave, lane);

    // ================= Layers 2 and 3: H(32x128) @ W(128x128) =================
    #pragma unroll 1
    for (int layer = 0; layer < 2; ++layer) {
        const unsigned short* wpL = wp + (layer == 0 ? 4096 : 20480);
        const float* bL  = (layer == 0) ? b2  : b3;
        const float* gL  = (layer == 0) ? g2  : g3;
        const float* beL = (layer == 0) ? be2 : be3;

        float bv[NT];
        #pragma unroll
        for (int nt = 0; nt < NT; ++nt) bv[nt] = bL[nt*16 + cl];

        bf16x8 a[2][KS2];
        #pragma unroll
        for (int mt = 0; mt < 2; ++mt) {
            const int row = 32*wave + 16*mt + cl;
            #pragma unroll
            for (int ks = 0; ks < KS2; ++ks) {
                const int cb = ks*4 + gq;
                a[mt][ks] = *(const bf16x8*)(&s_h[row*128 + ((cb ^ (row & 7)) << 3)]);
            }
        }
        #pragma unroll
        for (int nt = 0; nt < NT; ++nt) {
            bf16x8 bfr[KS2];
            #pragma unroll
            for (int ks = 0; ks < KS2; ++ks)
                bfr[ks] = *(const bf16x8*)(wpL + ((nt*KS2 + ks)*64 + lane)*8);
            #pragma unroll
            for (int mt = 0; mt < 2; ++mt) {
                f32x4 c = {bv[nt], bv[nt], bv[nt], bv[nt]};
                #pragma unroll
                for (int ks = 0; ks < KS2; ++ks)
                    c = __builtin_amdgcn_mfma_f32_16x16x32_bf16(a[mt][ks], bfr[ks], c, 0, 0, 0);
                acc[mt][nt] = c;
            }
        }
        ln_gelu_acc(acc, gL, beL, lane);
        if (layer == 0) store_h(acc, s_h, wave, lane);
    }

    // ================= mean over K=16 rows, write out =================
    #pragma unroll
    for (int mt = 0; mt < 2; ++mt) {
        const int n = n0 + 2*wave + mt;
        #pragma unroll
        for (int nt = 0; nt < NT; ++nt) {
            float sv = acc[mt][nt][0] + acc[mt][nt][1] + acc[mt][nt][2] + acc[mt][nt][3];
            sv += __shfl_xor(sv, 16, 64);
            sv += __shfl_xor(sv, 32, 64);
            if (gq == (nt >> 1))    // 16 lanes of the owning quad write 64B
                out[((size_t)b * Ndim + n) * Edim + nt*16 + cl] = sv * (1.0f/16.0f);
        }
    }
}

extern "C" void kernel_launch(void* const* d_in, const int* in_sizes, int n_in,
                              void* d_out, int out_size, void* d_ws, size_t ws_size,
                              hipStream_t stream)
{
    const float* x   = (const float*)d_in[0];
    const float* W1  = (const float*)d_in[1];
    const float* b1  = (const float*)d_in[2];
    const float* g1  = (const float*)d_in[3];
    const float* be1 = (const float*)d_in[4];
    const float* W2  = (const float*)d_in[5];
    const float* b2  = (const float*)d_in[6];
    const float* g2  = (const float*)d_in[7];
    const float* be2 = (const float*)d_in[8];
    const float* W3  = (const float*)d_in[9];
    const float* b3  = (const float*)d_in[10];
    const float* g3  = (const float*)d_in[11];
    const float* be3 = (const float*)d_in[12];
    float* out = (float*)d_out;
    unsigned short* wp = (unsigned short*)d_ws;

    hipLaunchKernelGGL(pack_w_kernel, dim3(144), dim3(256), 0, stream, W1, W2, W3, wp);
    hipLaunchKernelGGL(edgeconv_mfma, dim3((Bdim * Ndim) / PTS), dim3(128), 0, stream,
                       x, wp, b1, g1, be1, b2, g2, be2, b3, g3, be3, out);
}

// Round 5
// 196.199 us; speedup vs baseline: 5.0784x; 1.2968x over previous
//
#include <hip/hip_runtime.h>
#include <math.h>

#define Bdim 64
#define Ndim 512
#define Ddim 16
#define Kdim 16
#define Edim 128
#define LN_EPS 1e-5f

#define PTS   2     // points per block, ONE point per wave
#define NT    8     // 16-wide N tiles over E=128
#define KS2   4     // 32-deep K steps over E=128

typedef __attribute__((ext_vector_type(8))) short bf16x8;
typedef __attribute__((ext_vector_type(4))) float f32x4;

// RNE float -> bf16 bits
__device__ __forceinline__ unsigned short f2bf(float f) {
    unsigned u = __float_as_uint(f);
    unsigned r = (u + 0x7FFFu + ((u >> 16) & 1u)) >> 16;
    return (unsigned short)r;
}

// GELU, tanh-form via sigmoid identity: |err vs exact| <= ~4e-4, ~7 VALU ops.
__device__ __forceinline__ float gelu_fast(float x) {
    float x2 = x * x;
    float t  = fmaf(x2, -0.0713548162f, -1.5957691216f);
    float e  = __expf(x * t);                       // e^{-2g}
    return x * __builtin_amdgcn_rcpf(1.0f + e);
}

// ---------------- weight pre-pack: fp32 row-major [K][128] -> bf16 B-fragments
// layout: [nt][ks][lane][j], fragment elem j of lane l = W[ks*32 + 8*(l>>4)+j][nt*16 + (l&15)]
__global__ __launch_bounds__(256) void pack_w_kernel(
    const float* __restrict__ W1, const float* __restrict__ W2,
    const float* __restrict__ W3, unsigned short* __restrict__ wp)
{
    int idx = blockIdx.x * 256 + threadIdx.x;
    if (idx >= 36864) return;
    if (idx < 4096) {
        int t = idx;
        int nt = t >> 9, l = (t >> 3) & 63, j = t & 7;
        int k = 8 * (l >> 4) + j, n = nt * 16 + (l & 15);
        wp[idx] = f2bf(W1[k * Edim + n]);
    } else if (idx < 20480) {
        int t = idx - 4096;
        int nt = t >> 11, ks = (t >> 9) & 3, l = (t >> 3) & 63, j = t & 7;
        int k = ks * 32 + 8 * (l >> 4) + j, n = nt * 16 + (l & 15);
        wp[idx] = f2bf(W2[k * Edim + n]);
    } else {
        int t = idx - 20480;
        int nt = t >> 11, ks = (t >> 9) & 3, l = (t >> 3) & 63, j = t & 7;
        int k = ks * 32 + 8 * (l >> 4) + j, n = nt * 16 + (l & 15);
        wp[idx] = f2bf(W3[k * Edim + n]);
    }
}

// LayerNorm + GELU on the wave-private accumulator (one point).
// D layout per 16x16 tile: value j of lane l is H[row = 4*(l>>4) + j][col = nt*16 + (l&15)]
__device__ __forceinline__ void ln_gelu_acc(
    f32x4 acc[NT], const float* __restrict__ g, const float* __restrict__ be, int lane)
{
    const int cl = lane & 15;
    float s[4] = {0.f,0.f,0.f,0.f}, s2[4] = {0.f,0.f,0.f,0.f};
    #pragma unroll
    for (int nt = 0; nt < NT; ++nt)
        #pragma unroll
        for (int j = 0; j < 4; ++j) {
            float v = acc[nt][j];
            s[j] += v;
            s2[j] = fmaf(v, v, s2[j]);
        }
    #pragma unroll
    for (int off = 1; off < 16; off <<= 1)
        #pragma unroll
        for (int j = 0; j < 4; ++j) {
            s[j]  += __shfl_xor(s[j],  off, 64);
            s2[j] += __shfl_xor(s2[j], off, 64);
        }
    float mj[4], rj[4];
    #pragma unroll
    for (int j = 0; j < 4; ++j) {
        float m   = s[j]  * (1.0f/128.0f);
        float var = s2[j] * (1.0f/128.0f) - m * m;
        mj[j] = m;
        rj[j] = __builtin_amdgcn_rsqf(var + LN_EPS);
    }
    #pragma unroll
    for (int nt = 0; nt < NT; ++nt) {
        const float gv = g[nt*16 + cl], bev = be[nt*16 + cl];
        #pragma unroll
        for (int j = 0; j < 4; ++j) {
            float v = (acc[nt][j] - mj[j]) * rj[j];
            v = fmaf(v, gv, bev);
            acc[nt][j] = gelu_fast(v);
        }
    }
}

// store acc (bf16) to swizzled H: elem col c of row r lives at r*128 + ((c>>3 ^ (r&7))<<3) + (c&7)
__device__ __forceinline__ void store_h(
    const f32x4 acc[NT], unsigned short* __restrict__ s_h, int wave, int lane)
{
    const int cl = lane & 15, gq = lane >> 4;
    const int rbase = 16*wave + 4*gq;
    #pragma unroll
    for (int nt = 0; nt < NT; ++nt) {
        const int col = nt*16 + cl;
        const int cb  = col >> 3;
        #pragma unroll
        for (int j = 0; j < 4; ++j) {
            const int row = rbase + j;
            s_h[row*128 + ((cb ^ (row & 7)) << 3) + (col & 7)] = f2bf(acc[nt][j]);
        }
    }
}

__global__ __launch_bounds__(128, 4) void edgeconv_mfma(
    const float* __restrict__ x,
    const unsigned short* __restrict__ wp,
    const float* __restrict__ b1, const float* __restrict__ g1, const float* __restrict__ be1,
    const float* __restrict__ b2, const float* __restrict__ g2, const float* __restrict__ be2,
    const float* __restrict__ b3, const float* __restrict__ g3, const float* __restrict__ be3,
    float* __restrict__ out)
{
    const int tid  = threadIdx.x;
    const int wave = tid >> 6, lane = tid & 63;
    const int bp = blockIdx.x;
    const int b  = bp >> 8;              // 256 blocks per batch element
    const int n0 = (bp & 255) * PTS;
    const int n  = n0 + wave;            // this wave's point

    // only LDS: wave-private H rows (wave w owns rows 16w..16w+15). No barriers anywhere.
    __shared__ __align__(16) unsigned short s_h[32 * 128];         // 8 KB, XOR-swizzled

    const float* __restrict__ xb = x + (size_t)b * (Ndim * Ddim);
    const int cl = lane & 15, gq = lane >> 4;

    // ---- candidate xy coords into registers: lane holds points {c*64+lane} ----
    float cxr[8], cyr[8];
    #pragma unroll
    for (int c = 0; c < 8; ++c) {
        const float2 p2 = *(const float2*)(xb + (c * 64 + lane) * Ddim + 8);
        cxr[c] = p2.x; cyr[c] = p2.y;
    }

    // ---- KNN for this wave's point. Exact fp32 mul/mul/add; ties by lower idx.
    //      Lane cl captures the cl-th selected neighbor index in my_nb.
    unsigned my_nb = 0;
    {
        const float qx = xb[n * Ddim + 8], qy = xb[n * Ddim + 9];
        unsigned long long key[8];
        #pragma unroll
        for (int c = 0; c < 8; ++c) {
            int j = c * 64 + lane;
            float dx = __fsub_rn(qx, cxr[c]);
            float dy = __fsub_rn(qy, cyr[c]);
            float d2 = __fadd_rn(__fmul_rn(dx,dx), __fmul_rn(dy,dy));
            key[c] = ((unsigned long long)__float_as_uint(d2) << 32) | (unsigned)j;
        }
        for (int sel = 0; sel < Kdim; ++sel) {
            unsigned long long m = key[0];
            #pragma unroll
            for (int c = 1; c < 8; ++c) m = (key[c] < m) ? key[c] : m;
            #pragma unroll
            for (int off = 32; off > 0; off >>= 1) {
                unsigned long long o = __shfl_xor(m, off, 64);
                m = (o < m) ? o : m;
            }
            unsigned widx = (unsigned)m;
            if ((lane & 15) == sel) my_nb = widx;   // capture for all 4 gq quads
            const bool owner = ((widx & 63u) == (unsigned)lane);
            const unsigned co = widx >> 6;
            #pragma unroll
            for (int c = 0; c < 8; ++c)
                if (owner && co == (unsigned)c) key[c] = ~0ull;   // static index (no scratch)
        }
    }

    f32x4 acc[NT];

    // ================= Layer 1: feats(16x32) @ W1, A-fragment built in registers =================
    {
        const int off8 = (gq & 1) * 8;
        const float* pc = xb + n * Ddim + off8;
        const float* pn = xb + (int)my_nb * Ddim + off8;
        float4 c0 = *(const float4*)(pc);
        float4 c1 = *(const float4*)(pc + 4);
        float4 v0 = *(const float4*)(pn);
        float4 v1 = *(const float4*)(pn + 4);
        const bool diff = (gq >= 2);
        float e0 = diff ? (v0.x - c0.x) : c0.x;
        float e1 = diff ? (v0.y - c0.y) : c0.y;
        float e2 = diff ? (v0.z - c0.z) : c0.z;
        float e3 = diff ? (v0.w - c0.w) : c0.w;
        float e4 = diff ? (v1.x - c1.x) : c1.x;
        float e5 = diff ? (v1.y - c1.y) : c1.y;
        float e6 = diff ? (v1.z - c1.z) : c1.z;
        float e7 = diff ? (v1.w - c1.w) : c1.w;
        bf16x8 a1;
        a1[0] = (short)f2bf(e0); a1[1] = (short)f2bf(e1);
        a1[2] = (short)f2bf(e2); a1[3] = (short)f2bf(e3);
        a1[4] = (short)f2bf(e4); a1[5] = (short)f2bf(e5);
        a1[6] = (short)f2bf(e6); a1[7] = (short)f2bf(e7);

        #pragma unroll
        for (int nt = 0; nt < NT; ++nt) {
            const float bv = b1[nt*16 + cl];
            bf16x8 bfr = *(const bf16x8*)(wp + (nt*64 + lane)*8);
            f32x4 c = {bv, bv, bv, bv};
            acc[nt] = __builtin_amdgcn_mfma_f32_16x16x32_bf16(a1, bfr, c, 0, 0, 0);
        }
    }
    ln_gelu_acc(acc, g1, be1, lane);
    store_h(acc, s_h, wave, lane);

    // ================= Layers 2 and 3: H(16x128) @ W(128x128) =================
    #pragma unroll 1
    for (int layer = 0; layer < 2; ++layer) {
        const unsigned short* wpL = wp + (layer == 0 ? 4096 : 20480);
        const float* bL  = (layer == 0) ? b2  : b3;
        const float* gL  = (layer == 0) ? g2  : g3;
        const float* beL = (layer == 0) ? be2 : be3;

        bf16x8 a[KS2];
        {
            const int row = 16*wave + cl;
            #pragma unroll
            for (int ks = 0; ks < KS2; ++ks) {
                const int cb = ks*4 + gq;
                a[ks] = *(const bf16x8*)(&s_h[row*128 + ((cb ^ (row & 7)) << 3)]);
            }
        }
        #pragma unroll
        for (int nt = 0; nt < NT; ++nt) {
            const float bv = bL[nt*16 + cl];
            f32x4 c = {bv, bv, bv, bv};
            #pragma unroll
            for (int ks = 0; ks < KS2; ++ks) {
                bf16x8 bfr = *(const bf16x8*)(wpL + ((nt*KS2 + ks)*64 + lane)*8);
                c = __builtin_amdgcn_mfma_f32_16x16x32_bf16(a[ks], bfr, c, 0, 0, 0);
            }
            acc[nt] = c;
        }
        ln_gelu_acc(acc, gL, beL, lane);
        if (layer == 0) store_h(acc, s_h, wave, lane);
    }

    // ================= mean over K=16 rows, write out =================
    #pragma unroll
    for (int nt = 0; nt < NT; ++nt) {
        float sv = acc[nt][0] + acc[nt][1] + acc[nt][2] + acc[nt][3];
        sv += __shfl_xor(sv, 16, 64);
        sv += __shfl_xor(sv, 32, 64);
        if (gq == (nt >> 1))    // 16 lanes of the owning quad write 64B
            out[((size_t)b * Ndim + n) * Edim + nt*16 + cl] = sv * (1.0f/16.0f);
    }
}

extern "C" void kernel_launch(void* const* d_in, const int* in_sizes, int n_in,
                              void* d_out, int out_size, void* d_ws, size_t ws_size,
                              hipStream_t stream)
{
    const float* x   = (const float*)d_in[0];
    const float* W1  = (const float*)d_in[1];
    const float* b1  = (const float*)d_in[2];
    const float* g1  = (const float*)d_in[3];
    const float* be1 = (const float*)d_in[4];
    const float* W2  = (const float*)d_in[5];
    const float* b2  = (const float*)d_in[6];
    const float* g2  = (const float*)d_in[7];
    const float* be2 = (const float*)d_in[8];
    const float* W3  = (const float*)d_in[9];
    const float* b3  = (const float*)d_in[10];
    const float* g3  = (const float*)d_in[11];
    const float* be3 = (const float*)d_in[12];
    float* out = (float*)d_out;
    unsigned short* wp = (unsigned short*)d_ws;

    hipLaunchKernelGGL(pack_w_kernel, dim3(144), dim3(256), 0, stream, W1, W2, W3, wp);
    hipLaunchKernelGGL(edgeconv_mfma, dim3((Bdim * Ndim) / PTS), dim3(128), 0, stream,
                       x, wp, b1, g1, be1, b2, g2, be2, b3, g3, be3, out);
}